// Round 6
// baseline (1701.778 us; speedup 1.0000x reference)
//
#include <hip/hip_runtime.h>
#include <hip/hip_bf16.h>
#include <math.h>

#define BB 32
#define NN 512
#define LL 4096
#define GG 128
#define DD 64   // DIM
#define RS 20   // ga_V LDS row stride in u32 words: 16 packed-lpair words + 4 pad
#define AS 36   // ga_scores LDS row stride in u32 words: 32 words (64 bf16) + 4 pad

// ---- instrumentation: per-kernel repeat factors (measurement round only) ----
#define REP_NODES 64
#define REP_ADJT  40
#define REP_MLP   40
#define REP_SCORES 40
#define REP_V     3

typedef __attribute__((ext_vector_type(4))) float f32x4;
typedef __attribute__((ext_vector_type(8))) short bf16x8;
typedef __attribute__((ext_vector_type(4))) unsigned u32x4;
typedef __attribute__((ext_vector_type(4))) unsigned short u16x4;

__device__ inline float sx(float v, int m) { return __shfl_xor(v, m, 64); }

// ---------------- K1: node embeddings n1, n2  [N, DIM] ----------------
__global__ __launch_bounds__(64) void ga_nodes(
    const int* __restrict__ idx,
    const float* __restrict__ emb1, const float* __restrict__ emb2,
    const float* __restrict__ w1, const float* __restrict__ b1,
    const float* __restrict__ w2, const float* __restrict__ b2,
    float* __restrict__ n1, float* __restrict__ n2) {
  int i = blockIdx.x;
  int d = threadIdx.x;
  int ii = idx[i];
  const float* e1 = emb1 + ii * DD;
  const float* e2 = emb2 + ii * DD;
  #pragma unroll 1
  for (int rep = 0; rep < REP_NODES; ++rep) {
    asm volatile("" ::: "memory");
    float a1 = 0.f, a2 = 0.f;
    #pragma unroll 8
    for (int k = 0; k < DD; ++k) {
      a1 += e1[k] * w1[k * DD + d];
      a2 += e2[k] * w2[k * DD + d];
    }
    n1[i * DD + d] = tanhf(3.f * (a1 + b1[d]));
    n2[i * DD + d] = tanhf(3.f * (a2 + b2[d]));
  }
}

// ------ K2: adjT16[s][l] = adj[l][s] = tanh(3*(n1[l]·n2[s] - n2[l]·n1[s])), bf16
__global__ __launch_bounds__(256) void ga_adjT(
    const float* __restrict__ n1, const float* __restrict__ n2,
    __hip_bfloat16* __restrict__ adjT16) {
  int r = blockIdx.x;  // s index
  __shared__ float n1r[DD], n2r[DD];
  if (threadIdx.x < DD) {
    n1r[threadIdx.x] = n1[r * DD + threadIdx.x];
    n2r[threadIdx.x] = n2[r * DD + threadIdx.x];
  }
  __syncthreads();
  #pragma unroll 1
  for (int rep = 0; rep < REP_ADJT; ++rep) {
    asm volatile("" ::: "memory");
    for (int l = threadIdx.x; l < NN; l += 256) {
      const float4* p1 = (const float4*)(n1 + l * DD);
      const float4* p2 = (const float4*)(n2 + l * DD);
      float d1 = 0.f, d2 = 0.f;
      #pragma unroll
      for (int q = 0; q < DD / 4; ++q) {
        float4 v1 = p1[q], v2 = p2[q];
        float4 m2 = ((const float4*)n2r)[q];
        float4 m1 = ((const float4*)n1r)[q];
        d1 += v1.x * m2.x + v1.y * m2.y + v1.z * m2.z + v1.w * m2.w;
        d2 += v2.x * m1.x + v2.y * m1.y + v2.z * m1.z + v2.w * m1.w;
      }
      adjT16[r * NN + l] = __float2bfloat16(tanhf(3.f * (d1 - d2)));
    }
  }
}

// ---------------- K3: MLP + fused relu-select ----------------
__global__ __launch_bounds__(256) void ga_mlp(
    const float* __restrict__ x, const float* __restrict__ mlp_w,
    const float* __restrict__ mlp_b, const float* __restrict__ wsel,
    __hip_bfloat16* __restrict__ RT) {
  int b = blockIdx.y;
  int j0 = blockIdx.x * 8;   // x-row base, 0..56
  int n0 = j0 * 8;           // t/l base, 0..448
  int tid = threadIdx.x;
  __shared__ float red[4 * 64];
  __shared__ float tl[64];
  const float* xb = x + (size_t)b * NN * LL;
  int lane = tid & 63, wave = tid >> 6;

  #pragma unroll 1
  for (int rep = 0; rep < REP_MLP; ++rep) {
    asm volatile("" ::: "memory");
    float acc[8][8];
    #pragma unroll
    for (int j = 0; j < 8; ++j)
      #pragma unroll
      for (int c = 0; c < 8; ++c) acc[j][c] = 0.f;

    for (int lc = 0; lc < LL; lc += 256) {
      int l = lc + tid;
      float4 w0 = *(const float4*)(mlp_w + l * 8);
      float4 w1 = *(const float4*)(mlp_w + l * 8 + 4);
      #pragma unroll
      for (int j = 0; j < 8; ++j) {
        float xv = xb[(size_t)(j0 + j) * LL + l];
        acc[j][0] += xv * w0.x; acc[j][1] += xv * w0.y;
        acc[j][2] += xv * w0.z; acc[j][3] += xv * w0.w;
        acc[j][4] += xv * w1.x; acc[j][5] += xv * w1.y;
        acc[j][6] += xv * w1.z; acc[j][7] += xv * w1.w;
      }
    }
    #pragma unroll
    for (int j = 0; j < 8; ++j)
      #pragma unroll
      for (int c = 0; c < 8; ++c) {
        float v = acc[j][c];
        for (int off = 32; off; off >>= 1) v += __shfl_down(v, off);
        acc[j][c] = v;
      }
    if (lane == 0) {
      #pragma unroll
      for (int j = 0; j < 8; ++j)
        #pragma unroll
        for (int c = 0; c < 8; ++c) red[wave * 64 + j * 8 + c] = acc[j][c];
    }
    __syncthreads();
    if (tid < 64) {
      float s = red[tid] + red[64 + tid] + red[128 + tid] + red[192 + tid];
      tl[tid] = tanhf(s + mlp_b[tid & 7]);
    }
    __syncthreads();
    unsigned short* rp = (unsigned short*)RT + (size_t)b * GG * NN + n0;
    #pragma unroll
    for (int it = 0; it < 8; ++it) {
      int f = it * 256 + tid;
      int g = f >> 4, c = f & 15;
      float w = wsel[g];
      u16x4 pk;
      #pragma unroll
      for (int k = 0; k < 4; ++k)
        pk[k] = __bfloat16_as_ushort(__float2bfloat16(fmaxf(tl[4 * c + k] * w, 0.f)));
      *(u16x4*)(rp + (size_t)g * NN + 4 * c) = pk;
    }
    __syncthreads();
  }
}

// ---------------- K4 (MFMA): scores GEMM + fused softmax -> seriesT bf16 ----
__global__ __launch_bounds__(256) void ga_scores_mfma(
    const __hip_bfloat16* __restrict__ adjT16,
    const __hip_bfloat16* __restrict__ RT,
    __hip_bfloat16* __restrict__ seriesT) {
  int b = blockIdx.y;
  int s0 = blockIdx.x * 128;
  int tid = threadIdx.x;
  __shared__ unsigned As[128 * AS];  // [s_local][l words]
  __shared__ unsigned Bs[128 * AS];  // [g][l words]
  int wave = tid >> 6, lane = tid & 63, q = lane >> 4, mrow = lane & 15;
  const unsigned short* ap = (const unsigned short*)adjT16;
  const unsigned short* bp = (const unsigned short*)RT + (size_t)b * GG * NN;

  #pragma unroll 1
  for (int rep = 0; rep < REP_SCORES; ++rep) {
    asm volatile("" ::: "memory");
    f32x4 acc[2][8];
    #pragma unroll
    for (int mf = 0; mf < 2; ++mf)
      #pragma unroll
      for (int nf = 0; nf < 8; ++nf) acc[mf][nf] = (f32x4){0.f, 0.f, 0.f, 0.f};

    for (int l0 = 0; l0 < NN; l0 += 64) {
      #pragma unroll
      for (int it = 0; it < 4; ++it) {
        int ci = it * 256 + tid;
        int row = ci >> 3, part = ci & 7;
        u32x4 va = *(const u32x4*)(ap + (size_t)(s0 + row) * NN + l0 + part * 8);
        u32x4 vb = *(const u32x4*)(bp + (size_t)row * NN + l0 + part * 8);
        *(u32x4*)&As[row * AS + part * 4] = va;
        *(u32x4*)&Bs[row * AS + part * 4] = vb;
      }
      __syncthreads();
      #pragma unroll
      for (int ks = 0; ks < 2; ++ks) {
        bf16x8 af0 = *(const bf16x8*)&As[(wave * 32 + mrow) * AS + ks * 16 + q * 4];
        bf16x8 af1 = *(const bf16x8*)&As[(wave * 32 + 16 + mrow) * AS + ks * 16 + q * 4];
        #pragma unroll
        for (int nf = 0; nf < 8; ++nf) {
          bf16x8 bfr = *(const bf16x8*)&Bs[(nf * 16 + mrow) * AS + ks * 16 + q * 4];
          acc[0][nf] = __builtin_amdgcn_mfma_f32_16x16x32_bf16(af0, bfr, acc[0][nf], 0, 0, 0);
          acc[1][nf] = __builtin_amdgcn_mfma_f32_16x16x32_bf16(af1, bfr, acc[1][nf], 0, 0, 0);
        }
      }
      __syncthreads();
    }

    unsigned short* sT = (unsigned short*)seriesT + (size_t)b * GG * NN;
    #pragma unroll
    for (int mf = 0; mf < 2; ++mf) {
      f32x4 mx = acc[mf][0];
      #pragma unroll
      for (int nf = 1; nf < 8; ++nf)
        #pragma unroll
        for (int r = 0; r < 4; ++r) mx[r] = fmaxf(mx[r], acc[mf][nf][r]);
      #pragma unroll
      for (int m = 1; m <= 8; m <<= 1)
        #pragma unroll
        for (int r = 0; r < 4; ++r) mx[r] = fmaxf(mx[r], sx(mx[r], m));
      f32x4 sum = (f32x4){0.f, 0.f, 0.f, 0.f};
      #pragma unroll
      for (int nf = 0; nf < 8; ++nf)
        #pragma unroll
        for (int r = 0; r < 4; ++r) {
          float e = __expf(acc[mf][nf][r] - mx[r]);
          acc[mf][nf][r] = e;
          sum[r] += e;
        }
      #pragma unroll
      for (int m = 1; m <= 8; m <<= 1)
        #pragma unroll
        for (int r = 0; r < 4; ++r) sum[r] += sx(sum[r], m);
      f32x4 inv;
      #pragma unroll
      for (int r = 0; r < 4; ++r) inv[r] = 1.f / sum[r];
      int sbase = s0 + wave * 32 + mf * 16 + q * 4;
      #pragma unroll
      for (int nf = 0; nf < 8; ++nf) {
        u16x4 pk;
        #pragma unroll
        for (int r = 0; r < 4; ++r)
          pk[r] = __bfloat16_as_ushort(__float2bfloat16(acc[mf][nf][r] * inv[r]));
        *(u16x4*)(sT + (size_t)(nf * 16 + mrow) * NN + sbase) = pk;
      }
    }
  }
}

// ---------------- K5 (MFMA): out[b,p,g] = sum_l x[b,l,p] * seriesT[b,g,l]
// M=4096 (p), N=128 (g), K=512 (l). Block: 4 waves, tile 128p x 128g, K-step 32.
// (R4 single-buffer structure; R5 explicit pipeline was neutral -> dropped.)
__global__ __launch_bounds__(256) void ga_V_mfma(
    const float* __restrict__ x, const __hip_bfloat16* __restrict__ seriesT,
    float* __restrict__ out) {
  int b = blockIdx.y;
  int p0 = blockIdx.x * 128;
  int tid = threadIdx.x;

  __shared__ unsigned Xt[128 * RS];  // [p_local][lpair] packed bf16x2
  __shared__ unsigned St[128 * RS];  // [g][lpair]

  int i = tid & 31;
  int j = tid >> 5;
  int wave = tid >> 6, lane = tid & 63, q = lane >> 4, mrow = lane & 15;

  const float* xb = x + (size_t)b * NN * LL + p0;
  const unsigned short* sb = (const unsigned short*)seriesT + (size_t)b * GG * NN;

  #pragma unroll 1
  for (int rep = 0; rep < REP_V; ++rep) {
    asm volatile("" ::: "memory");
    f32x4 acc[2][8];
    #pragma unroll
    for (int mf = 0; mf < 2; ++mf)
      #pragma unroll
      for (int nf = 0; nf < 8; ++nf) acc[mf][nf] = (f32x4){0.f, 0.f, 0.f, 0.f};

    for (int l0 = 0; l0 < NN; l0 += 32) {
      #pragma unroll
      for (int h = 0; h < 2; ++h) {
        int lp = j + 8 * h;
        const float* xr0 = xb + (size_t)(l0 + 2 * lp) * LL;
        const float* xr1 = xr0 + LL;
        #pragma unroll
        for (int c = 0; c < 4; ++c) {
          int p = i + 32 * c;
          __hip_bfloat162 pk = __float22bfloat162_rn(make_float2(xr0[p], xr1[p]));
          Xt[p * RS + lp] = *(unsigned*)&pk;
        }
      }
      {
        int c0 = tid;
        int g = c0 >> 2, part = c0 & 3;
        *(u32x4*)&St[g * RS + part * 4] =
            *(const u32x4*)(sb + (size_t)g * NN + l0 + part * 8);
        int c1 = tid + 256;
        g = c1 >> 2; part = c1 & 3;
        *(u32x4*)&St[g * RS + part * 4] =
            *(const u32x4*)(sb + (size_t)g * NN + l0 + part * 8);
      }
      __syncthreads();

      bf16x8 af[2];
      #pragma unroll
      for (int mf = 0; mf < 2; ++mf) {
        int row = wave * 32 + mf * 16 + mrow;
        af[mf] = *(const bf16x8*)&Xt[row * RS + q * 4];
      }
      #pragma unroll
      for (int nf = 0; nf < 8; ++nf) {
        bf16x8 bfr = *(const bf16x8*)&St[(nf * 16 + mrow) * RS + q * 4];
        acc[0][nf] = __builtin_amdgcn_mfma_f32_16x16x32_bf16(af[0], bfr, acc[0][nf], 0, 0, 0);
        acc[1][nf] = __builtin_amdgcn_mfma_f32_16x16x32_bf16(af[1], bfr, acc[1][nf], 0, 0, 0);
      }
      __syncthreads();
    }

    #pragma unroll
    for (int mf = 0; mf < 2; ++mf) {
      int pb = p0 + wave * 32 + mf * 16 + q * 4;
      #pragma unroll
      for (int nf = 0; nf < 8; ++nf) {
        int g = nf * 16 + mrow;
        float* op = out + ((size_t)b * LL + pb) * GG + g;
        #pragma unroll
        for (int r = 0; r < 4; ++r) op[(size_t)r * GG] = acc[mf][nf][r];
      }
    }
  }
}

extern "C" void kernel_launch(void* const* d_in, const int* in_sizes, int n_in,
                              void* d_out, int out_size, void* d_ws, size_t ws_size,
                              hipStream_t stream) {
  const int*   idx    = (const int*)d_in[0];
  const float* x      = (const float*)d_in[5];
  const float* emb1   = (const float*)d_in[6];
  const float* emb2   = (const float*)d_in[7];
  const float* lin1_w = (const float*)d_in[8];
  const float* lin1_b = (const float*)d_in[9];
  const float* lin2_w = (const float*)d_in[10];
  const float* lin2_b = (const float*)d_in[11];
  const float* mlp_w  = (const float*)d_in[12];
  const float* mlp_b  = (const float*)d_in[13];
  const float* W_sel  = (const float*)d_in[14];  // [8,128,1]; only h=0 row used
  float* out = (float*)d_out;

  float* ws = (float*)d_ws;
  float* n1 = ws;                                        // 32768 floats
  float* n2 = ws + 32768;                                // 32768 floats
  __hip_bfloat16* adjT16  = (__hip_bfloat16*)(ws + 65536);    // 512*512 bf16
  __hip_bfloat16* RT      = (__hip_bfloat16*)(ws + 196608);   // 32*128*512 bf16
  __hip_bfloat16* seriesT = (__hip_bfloat16*)(ws + 1245184);  // 32*128*512 bf16

  ga_nodes<<<NN, 64, 0, stream>>>(idx, emb1, emb2, lin1_w, lin1_b,
                                  lin2_w, lin2_b, n1, n2);
  ga_adjT<<<NN, 256, 0, stream>>>(n1, n2, adjT16);
  ga_mlp<<<dim3(8, BB), 256, 0, stream>>>(x, mlp_w, mlp_b, W_sel, RT);
  ga_scores_mfma<<<dim3(4, BB), 256, 0, stream>>>(adjT16, RT, seriesT);
  ga_V_mfma<<<dim3(LL / 128, BB), 256, 0, stream>>>(x, seriesT, out);
}

// Round 7
// 125.055 us; speedup vs baseline: 13.6083x; 13.6083x over previous
//
#include <hip/hip_runtime.h>
#include <hip/hip_bf16.h>
#include <math.h>

#define BB 32
#define NN 512
#define LL 4096
#define GG 128
#define DD 64   // DIM
#define RS 20   // ga_V LDS row stride in u32 words: 16 packed-lpair words + 4 pad
#define AS 36   // ga_scores LDS row stride in u32 words: 32 words (64 bf16) + 4 pad

typedef __attribute__((ext_vector_type(4))) float f32x4;
typedef __attribute__((ext_vector_type(8))) short bf16x8;
typedef __attribute__((ext_vector_type(4))) unsigned u32x4;
typedef __attribute__((ext_vector_type(4))) unsigned short u16x4;

__device__ inline float sx(float v, int m) { return __shfl_xor(v, m, 64); }

// ---------------- K1: node embeddings n1, n2  [N, DIM] ----------------
__global__ __launch_bounds__(64) void ga_nodes(
    const int* __restrict__ idx,
    const float* __restrict__ emb1, const float* __restrict__ emb2,
    const float* __restrict__ w1, const float* __restrict__ b1,
    const float* __restrict__ w2, const float* __restrict__ b2,
    float* __restrict__ n1, float* __restrict__ n2) {
  int i = blockIdx.x;
  int d = threadIdx.x;
  int ii = idx[i];
  const float* e1 = emb1 + ii * DD;
  const float* e2 = emb2 + ii * DD;
  float a1 = 0.f, a2 = 0.f;
  #pragma unroll 8
  for (int k = 0; k < DD; ++k) {
    a1 += e1[k] * w1[k * DD + d];
    a2 += e2[k] * w2[k * DD + d];
  }
  n1[i * DD + d] = tanhf(3.f * (a1 + b1[d]));
  n2[i * DD + d] = tanhf(3.f * (a2 + b2[d]));
}

// ------ K2: adjT16[s][l] = tanh(3*(n1[l]·n2[s] - n2[l]·n1[s])), bf16 ------
// Latency-bound fix (R6 counters: VALUBusy 12%, Occ 22%): 2048 blocks
// (dim3(4,NN), 128 thr, 1 l/thread) -> 16 waves/CU of independent L2 loads.
__global__ __launch_bounds__(128) void ga_adjT(
    const float* __restrict__ n1, const float* __restrict__ n2,
    __hip_bfloat16* __restrict__ adjT16) {
  int s = blockIdx.y;
  int l = blockIdx.x * 128 + threadIdx.x;
  __shared__ float n1r[DD], n2r[DD];
  if (threadIdx.x < DD) {
    n1r[threadIdx.x] = n1[s * DD + threadIdx.x];
    n2r[threadIdx.x] = n2[s * DD + threadIdx.x];
  }
  __syncthreads();
  const float4* p1 = (const float4*)(n1 + l * DD);
  const float4* p2 = (const float4*)(n2 + l * DD);
  float d1 = 0.f, d2 = 0.f;
  #pragma unroll
  for (int q = 0; q < DD / 4; ++q) {
    float4 v1 = p1[q], v2 = p2[q];
    float4 m2 = ((const float4*)n2r)[q];
    float4 m1 = ((const float4*)n1r)[q];
    d1 += v1.x * m2.x + v1.y * m2.y + v1.z * m2.z + v1.w * m2.w;
    d2 += v2.x * m1.x + v2.y * m1.y + v2.z * m1.z + v2.w * m1.w;
  }
  adjT16[s * NN + l] = __float2bfloat16(tanhf(3.f * (d1 - d2)));
}

// ---------------- K3: MLP + fused relu-select (512 thr = 8 waves/CU) -------
__global__ __launch_bounds__(512) void ga_mlp(
    const float* __restrict__ x, const float* __restrict__ mlp_w,
    const float* __restrict__ mlp_b, const float* __restrict__ wsel,
    __hip_bfloat16* __restrict__ RT) {
  int b = blockIdx.y;
  int j0 = blockIdx.x * 8;   // x-row base, 0..56
  int n0 = j0 * 8;           // t/l base, 0..448
  int tid = threadIdx.x;
  float acc[8][8];
  #pragma unroll
  for (int j = 0; j < 8; ++j)
    #pragma unroll
    for (int c = 0; c < 8; ++c) acc[j][c] = 0.f;

  const float* xb = x + (size_t)b * NN * LL;
  for (int lc = 0; lc < LL; lc += 512) {
    int l = lc + tid;
    float4 w0 = *(const float4*)(mlp_w + l * 8);
    float4 w1 = *(const float4*)(mlp_w + l * 8 + 4);
    #pragma unroll
    for (int j = 0; j < 8; ++j) {
      float xv = xb[(size_t)(j0 + j) * LL + l];
      acc[j][0] += xv * w0.x; acc[j][1] += xv * w0.y;
      acc[j][2] += xv * w0.z; acc[j][3] += xv * w0.w;
      acc[j][4] += xv * w1.x; acc[j][5] += xv * w1.y;
      acc[j][6] += xv * w1.z; acc[j][7] += xv * w1.w;
    }
  }
  #pragma unroll
  for (int j = 0; j < 8; ++j)
    #pragma unroll
    for (int c = 0; c < 8; ++c) {
      float v = acc[j][c];
      for (int off = 32; off; off >>= 1) v += __shfl_down(v, off);
      acc[j][c] = v;
    }
  __shared__ float red[8 * 64];
  __shared__ float tl[64];
  int lane = tid & 63, wave = tid >> 6;
  if (lane == 0) {
    #pragma unroll
    for (int j = 0; j < 8; ++j)
      #pragma unroll
      for (int c = 0; c < 8; ++c) red[wave * 64 + j * 8 + c] = acc[j][c];
  }
  __syncthreads();
  if (tid < 64) {
    float s = 0.f;
    #pragma unroll
    for (int w = 0; w < 8; ++w) s += red[w * 64 + tid];
    tl[tid] = tanhf(s + mlp_b[tid & 7]);
  }
  __syncthreads();
  unsigned short* rp = (unsigned short*)RT + (size_t)b * GG * NN + n0;
  #pragma unroll
  for (int it = 0; it < 4; ++it) {
    int f = it * 512 + tid;
    int g = f >> 4, c = f & 15;
    float w = wsel[g];
    u16x4 pk;
    #pragma unroll
    for (int k = 0; k < 4; ++k)
      pk[k] = __bfloat16_as_ushort(__float2bfloat16(fmaxf(tl[4 * c + k] * w, 0.f)));
    *(u16x4*)(rp + (size_t)g * NN + 4 * c) = pk;
  }
}

// ---------------- K4 (MFMA): scores GEMM + fused softmax -> seriesT bf16 ----
// 64s x 128g tile, grid dim3(8, BB) = 256 blocks (1/CU; R6: 128 blocks left
// half the CUs idle). Wave w owns s-rows [w*16, w*16+16).
__global__ __launch_bounds__(256) void ga_scores_mfma(
    const __hip_bfloat16* __restrict__ adjT16,
    const __hip_bfloat16* __restrict__ RT,
    __hip_bfloat16* __restrict__ seriesT) {
  int b = blockIdx.y;
  int s0 = blockIdx.x * 64;
  int tid = threadIdx.x;
  __shared__ unsigned As[64 * AS];   // [s_local][l words]
  __shared__ unsigned Bs[128 * AS];  // [g][l words]
  int wave = tid >> 6, lane = tid & 63, q = lane >> 4, mrow = lane & 15;
  const unsigned short* ap = (const unsigned short*)adjT16;
  const unsigned short* bp = (const unsigned short*)RT + (size_t)b * GG * NN;

  f32x4 acc[8];
  #pragma unroll
  for (int nf = 0; nf < 8; ++nf) acc[nf] = (f32x4){0.f, 0.f, 0.f, 0.f};

  for (int l0 = 0; l0 < NN; l0 += 64) {
    #pragma unroll
    for (int it = 0; it < 2; ++it) {   // A: 64 rows x 8 parts
      int ci = it * 256 + tid;
      int row = ci >> 3, part = ci & 7;
      *(u32x4*)&As[row * AS + part * 4] =
          *(const u32x4*)(ap + (size_t)(s0 + row) * NN + l0 + part * 8);
    }
    #pragma unroll
    for (int it = 0; it < 4; ++it) {   // B: 128 rows x 8 parts
      int ci = it * 256 + tid;
      int row = ci >> 3, part = ci & 7;
      *(u32x4*)&Bs[row * AS + part * 4] =
          *(const u32x4*)(bp + (size_t)row * NN + l0 + part * 8);
    }
    __syncthreads();
    #pragma unroll
    for (int ks = 0; ks < 2; ++ks) {
      bf16x8 af = *(const bf16x8*)&As[(wave * 16 + mrow) * AS + ks * 16 + q * 4];
      #pragma unroll
      for (int nf = 0; nf < 8; ++nf) {
        bf16x8 bfr = *(const bf16x8*)&Bs[(nf * 16 + mrow) * AS + ks * 16 + q * 4];
        acc[nf] = __builtin_amdgcn_mfma_f32_16x16x32_bf16(af, bfr, acc[nf], 0, 0, 0);
      }
    }
    __syncthreads();
  }

  // softmax over g; row (local) = q*4 + r, s = s0 + wave*16 + q*4 + r
  unsigned short* sT = (unsigned short*)seriesT + (size_t)b * GG * NN;
  f32x4 mx = acc[0];
  #pragma unroll
  for (int nf = 1; nf < 8; ++nf)
    #pragma unroll
    for (int r = 0; r < 4; ++r) mx[r] = fmaxf(mx[r], acc[nf][r]);
  #pragma unroll
  for (int m = 1; m <= 8; m <<= 1)
    #pragma unroll
    for (int r = 0; r < 4; ++r) mx[r] = fmaxf(mx[r], sx(mx[r], m));
  f32x4 sum = (f32x4){0.f, 0.f, 0.f, 0.f};
  #pragma unroll
  for (int nf = 0; nf < 8; ++nf)
    #pragma unroll
    for (int r = 0; r < 4; ++r) {
      float e = __expf(acc[nf][r] - mx[r]);
      acc[nf][r] = e;
      sum[r] += e;
    }
  #pragma unroll
  for (int m = 1; m <= 8; m <<= 1)
    #pragma unroll
    for (int r = 0; r < 4; ++r) sum[r] += sx(sum[r], m);
  f32x4 inv;
  #pragma unroll
  for (int r = 0; r < 4; ++r) inv[r] = 1.f / sum[r];
  int sbase = s0 + wave * 16 + q * 4;
  #pragma unroll
  for (int nf = 0; nf < 8; ++nf) {
    u16x4 pk;
    #pragma unroll
    for (int r = 0; r < 4; ++r)
      pk[r] = __bfloat16_as_ushort(__float2bfloat16(acc[nf][r] * inv[r]));
    *(u16x4*)(sT + (size_t)(nf * 16 + mrow) * NN + sbase) = pk;
  }
}

// ---------------- K5 (MFMA): out[b,p,g] = sum_l x[b,l,p] * seriesT[b,g,l]
// M=4096 (p), N=128 (g), K=512 (l). Block: 4 waves, tile 128p x 128g, K-step 32.
__global__ __launch_bounds__(256) void ga_V_mfma(
    const float* __restrict__ x, const __hip_bfloat16* __restrict__ seriesT,
    float* __restrict__ out) {
  int b = blockIdx.y;
  int p0 = blockIdx.x * 128;
  int tid = threadIdx.x;

  __shared__ unsigned Xt[128 * RS];  // [p_local][lpair] packed bf16x2
  __shared__ unsigned St[128 * RS];  // [g][lpair]

  int i = tid & 31;
  int j = tid >> 5;
  int wave = tid >> 6, lane = tid & 63, q = lane >> 4, mrow = lane & 15;

  const float* xb = x + (size_t)b * NN * LL + p0;
  const unsigned short* sb = (const unsigned short*)seriesT + (size_t)b * GG * NN;

  f32x4 acc[2][8];
  #pragma unroll
  for (int mf = 0; mf < 2; ++mf)
    #pragma unroll
    for (int nf = 0; nf < 8; ++nf) acc[mf][nf] = (f32x4){0.f, 0.f, 0.f, 0.f};

  for (int l0 = 0; l0 < NN; l0 += 32) {
    #pragma unroll
    for (int h = 0; h < 2; ++h) {
      int lp = j + 8 * h;
      const float* xr0 = xb + (size_t)(l0 + 2 * lp) * LL;
      const float* xr1 = xr0 + LL;
      #pragma unroll
      for (int c = 0; c < 4; ++c) {
        int p = i + 32 * c;
        __hip_bfloat162 pk = __float22bfloat162_rn(make_float2(xr0[p], xr1[p]));
        Xt[p * RS + lp] = *(unsigned*)&pk;
      }
    }
    {
      int c0 = tid;
      int g = c0 >> 2, part = c0 & 3;
      *(u32x4*)&St[g * RS + part * 4] =
          *(const u32x4*)(sb + (size_t)g * NN + l0 + part * 8);
      int c1 = tid + 256;
      g = c1 >> 2; part = c1 & 3;
      *(u32x4*)&St[g * RS + part * 4] =
          *(const u32x4*)(sb + (size_t)g * NN + l0 + part * 8);
    }
    __syncthreads();

    bf16x8 af[2];
    #pragma unroll
    for (int mf = 0; mf < 2; ++mf) {
      int row = wave * 32 + mf * 16 + mrow;
      af[mf] = *(const bf16x8*)&Xt[row * RS + q * 4];
    }
    #pragma unroll
    for (int nf = 0; nf < 8; ++nf) {
      bf16x8 bfr = *(const bf16x8*)&St[(nf * 16 + mrow) * RS + q * 4];
      acc[0][nf] = __builtin_amdgcn_mfma_f32_16x16x32_bf16(af[0], bfr, acc[0][nf], 0, 0, 0);
      acc[1][nf] = __builtin_amdgcn_mfma_f32_16x16x32_bf16(af[1], bfr, acc[1][nf], 0, 0, 0);
    }
    __syncthreads();
  }

  #pragma unroll
  for (int mf = 0; mf < 2; ++mf) {
    int pb = p0 + wave * 32 + mf * 16 + q * 4;
    #pragma unroll
    for (int nf = 0; nf < 8; ++nf) {
      int g = nf * 16 + mrow;
      float* op = out + ((size_t)b * LL + pb) * GG + g;
      #pragma unroll
      for (int r = 0; r < 4; ++r) op[(size_t)r * GG] = acc[mf][nf][r];
    }
  }
}

extern "C" void kernel_launch(void* const* d_in, const int* in_sizes, int n_in,
                              void* d_out, int out_size, void* d_ws, size_t ws_size,
                              hipStream_t stream) {
  const int*   idx    = (const int*)d_in[0];
  const float* x      = (const float*)d_in[5];
  const float* emb1   = (const float*)d_in[6];
  const float* emb2   = (const float*)d_in[7];
  const float* lin1_w = (const float*)d_in[8];
  const float* lin1_b = (const float*)d_in[9];
  const float* lin2_w = (const float*)d_in[10];
  const float* lin2_b = (const float*)d_in[11];
  const float* mlp_w  = (const float*)d_in[12];
  const float* mlp_b  = (const float*)d_in[13];
  const float* W_sel  = (const float*)d_in[14];  // [8,128,1]; only h=0 row used
  float* out = (float*)d_out;

  float* ws = (float*)d_ws;
  float* n1 = ws;                                        // 32768 floats
  float* n2 = ws + 32768;                                // 32768 floats
  __hip_bfloat16* adjT16  = (__hip_bfloat16*)(ws + 65536);    // 512*512 bf16
  __hip_bfloat16* RT      = (__hip_bfloat16*)(ws + 196608);   // 32*128*512 bf16
  __hip_bfloat16* seriesT = (__hip_bfloat16*)(ws + 1245184);  // 32*128*512 bf16

  ga_nodes<<<NN, 64, 0, stream>>>(idx, emb1, emb2, lin1_w, lin1_b,
                                  lin2_w, lin2_b, n1, n2);
  ga_adjT<<<dim3(4, NN), 128, 0, stream>>>(n1, n2, adjT16);
  ga_mlp<<<dim3(8, BB), 512, 0, stream>>>(x, mlp_w, mlp_b, W_sel, RT);
  ga_scores_mfma<<<dim3(8, BB), 256, 0, stream>>>(adjT16, RT, seriesT);
  ga_V_mfma<<<dim3(LL / 128, BB), 256, 0, stream>>>(x, seriesT, out);
}